// Round 1
// baseline (33.040 us; speedup 1.0000x reference)
//
#include <hip/hip_runtime.h>
#include <stdint.h>

#define N2 361   // 19*19

// One block per board row b. 384 threads; threads [0,361) each own one move i.
// LDS holds the two per-player XOR delta tables for this row's player.
__global__ __launch_bounds__(384)
void superko_hash_kernel(const void* __restrict__ legal_p,      // (B,N2) bool or int32/float32
                         const int*  __restrict__ cur_player,   // (B,)
                         const int*  __restrict__ cur_hash,     // (B,)
                         const int*  __restrict__ Z,            // (3,N2) int32
                         const void* __restrict__ cap_p,        // (B,N2) bool or int32/float32
                         const int*  __restrict__ indptr,       // (B*N2+1,) int32
                         const int*  __restrict__ cap_idx,      // (L,) int32
                         int*        __restrict__ out)          // (B,N2) int32
{
    __shared__ int P_lds[N2];   // place delta:   Z0 ^ Z[p+1]
    __shared__ int D_lds[N2];   // capture delta: Z0 ^ Z[2-p]
    __shared__ int layout4;     // 1 => masks are 4-byte elements, 0 => 1-byte

    const int b   = blockIdx.x;
    const int tid = threadIdx.x;

    if (tid == 0) {
        // Classify mask element width from the first 16 words of legal_mask.
        // int32 masks: words in {0,1}. float32 masks: words in {0,0x3f800000}.
        // bool (byte) masks: 4 packed 0/1 bytes per word — P(all 16 words
        // look like the 4-byte patterns) = 8^-16, negligible.
        const uint32_t* w = (const uint32_t*)legal_p;
        int all4 = 1;
        #pragma unroll
        for (int k = 0; k < 16; ++k) {
            uint32_t v = w[k];
            if (!(v == 0u || v == 1u || v == 0x3f800000u)) all4 = 0;
        }
        layout4 = all4;
    }

    const int p = cur_player[b];   // 0 or 1 (wave-uniform -> scalar load)
    const int h = cur_hash[b];

    if (tid < N2) {
        int z0 = Z[tid];
        int z1 = Z[N2 + tid];
        int z2 = Z[2 * N2 + tid];
        int a = z0 ^ z1;           // p==0: place delta ; p==1: capture delta
        int c = z0 ^ z2;           // p==0: capture delta ; p==1: place delta
        P_lds[tid] = p ? c : a;
        D_lds[tid] = p ? a : c;
    }
    __syncthreads();

    if (tid >= N2) return;

    const int r = b * N2 + tid;

    bool legal, cap;
    if (layout4) {
        legal = ((const int*)legal_p)[r] != 0;   // works for int32 AND float32
        cap   = ((const int*)cap_p)[r]   != 0;   // (0x3f800000 != 0)
    } else {
        legal = ((const uint8_t*)legal_p)[r] != 0;
        cap   = ((const uint8_t*)cap_p)[r]   != 0;
    }

    int acc = 0;
    if (legal & cap) {
        // Segment XOR-reduce. Empty segment -> acc stays 0, which also
        // implements the (lens > 0) part of `keep`.
        int s = indptr[r];
        int e = indptr[r + 1];
        for (int j = s; j < e; ++j) {
            acc ^= D_lds[cap_idx[j]];
        }
    }

    out[r] = h ^ P_lds[tid] ^ acc;
}

extern "C" void kernel_launch(void* const* d_in, const int* in_sizes, int n_in,
                              void* d_out, int out_size, void* d_ws, size_t ws_size,
                              hipStream_t stream) {
    // Input order per setup_inputs():
    // 0: legal_mask (B,N2)  1: current_player (B,)  2: current_hash (B,)
    // 3: ZposT (3,N2)       4: can_capture_any (B,N2)
    // 5: cap_indptr (B*N2+1,)  6: cap_indices (L,)
    const void* legal  = d_in[0];
    const int*  player = (const int*)d_in[1];
    const int*  hash   = (const int*)d_in[2];
    const int*  Z      = (const int*)d_in[3];
    const void* cap    = d_in[4];
    const int*  indptr = (const int*)d_in[5];
    const int*  capidx = (const int*)d_in[6];
    int*        out    = (int*)d_out;

    const int B = in_sizes[1];   // 8192

    superko_hash_kernel<<<B, 384, 0, stream>>>(legal, player, hash, Z, cap,
                                               indptr, capidx, out);
}

// Round 2
// 29.530 us; speedup vs baseline: 1.1189x; 1.1189x over previous
//
#include <hip/hip_runtime.h>
#include <stdint.h>

#define N2 361   // 19*19

// One block per board row b. 384 threads; threads [0,361) each own one move i.
__global__ __launch_bounds__(384)
void superko_hash_kernel(const void* __restrict__ legal_p,      // (B,N2) bool or int32/float32
                         const int*  __restrict__ cur_player,   // (B,)
                         const int*  __restrict__ cur_hash,     // (B,)
                         const int*  __restrict__ Z,            // (3,N2) int32
                         const void* __restrict__ cap_p,        // (B,N2) bool or int32/float32
                         const int*  __restrict__ indptr,       // (B*N2+1,) int32
                         const int*  __restrict__ cap_idx,      // (L,) int32
                         int*        __restrict__ out,          // (B,N2) int32
                         int Lm1)                               // L-1 (clamp bound)
{
    __shared__ int D_lds[N2];   // capture delta table: Z0 ^ Z[2-p]

    const int b      = blockIdx.x;
    const int tid    = threadIdx.x;
    const bool active = tid < N2;
    const int r      = b * N2 + (active ? tid : 0);

    // ---- Issue all front-end loads as early & independently as possible ----

    // (a) Layout detection: wave-uniform reads of the first 16 words of
    // legal_mask. int32 masks -> words in {0,1}; float32 -> {0,0x3f800000};
    // byte (bool) masks virtually never match all 16 (P ~ 8^-16 on random
    // 0/1 bytes). Uniform address -> compiler emits scalar loads.
    const uint32_t* w = (const uint32_t*)legal_p;
    bool layout4 = true;
    #pragma unroll
    for (int k = 0; k < 16; ++k) {
        uint32_t v = w[k];
        layout4 = layout4 && (v == 0u || v == 1u || v == 0x3f800000u);
    }

    // (b) Segment bounds: unconditional, independent of the masks.
    const int s = indptr[r];
    const int e = indptr[r + 1];

    // (c) Wave-uniform scalars.
    const int p = cur_player[b];
    const int h = cur_hash[b];

    // (d) Zobrist delta tables; place delta stays in-register (only ever
    // read by the thread that computes it), capture delta goes to LDS.
    int place = 0;
    if (active) {
        int z0 = Z[tid];
        int z1 = Z[N2 + tid];
        int z2 = Z[2 * N2 + tid];
        int a = z0 ^ z1;           // p==0: place ; p==1: capture
        int c = z0 ^ z2;           // p==0: capture ; p==1: place
        place = p ? c : a;
        D_lds[tid] = p ? a : c;
    }

    // (e) Masks (depend only on the layout flag).
    bool legal = false, cap = false;
    if (active) {
        if (layout4) {
            legal = ((const int*)legal_p)[r] != 0;     // int32 or float32 bits
            cap   = ((const int*)cap_p)[r]   != 0;
        } else {
            legal = ((const uint8_t*)legal_p)[r] != 0;
            cap   = ((const uint8_t*)cap_p)[r]   != 0;
        }
    }

    __syncthreads();   // D_lds ready

    int acc = 0;
    const int len = e - s;
    if (active && legal && cap && len > 0) {
        if (len <= 8) {
            // Fully unrolled: 8 independent clamped loads issue back-to-back
            // (single memory latency instead of `len` serial ones). Clamped
            // addresses stay in-bounds; cap_idx values are always < N2 so
            // the LDS lookups are safe even for the k >= len lanes.
            int idxs[8];
            #pragma unroll
            for (int k = 0; k < 8; ++k) {
                int j = s + k;
                idxs[k] = cap_idx[j > Lm1 ? Lm1 : j];
            }
            #pragma unroll
            for (int k = 0; k < 8; ++k) {
                acc ^= (k < len) ? D_lds[idxs[k]] : 0;
            }
        } else {
            for (int j = s; j < e; ++j) acc ^= D_lds[cap_idx[j]];
        }
    }

    if (active) out[r] = h ^ place ^ acc;
}

extern "C" void kernel_launch(void* const* d_in, const int* in_sizes, int n_in,
                              void* d_out, int out_size, void* d_ws, size_t ws_size,
                              hipStream_t stream) {
    // 0: legal_mask (B,N2)  1: current_player (B,)  2: current_hash (B,)
    // 3: ZposT (3,N2)       4: can_capture_any (B,N2)
    // 5: cap_indptr (B*N2+1,)  6: cap_indices (L,)
    const void* legal  = d_in[0];
    const int*  player = (const int*)d_in[1];
    const int*  hash   = (const int*)d_in[2];
    const int*  Z      = (const int*)d_in[3];
    const void* cap    = d_in[4];
    const int*  indptr = (const int*)d_in[5];
    const int*  capidx = (const int*)d_in[6];
    int*        out    = (int*)d_out;

    const int B   = in_sizes[1];          // 8192
    const int Lm1 = in_sizes[6] - 1;      // last valid cap_indices element

    superko_hash_kernel<<<B, 384, 0, stream>>>(legal, player, hash, Z, cap,
                                               indptr, capidx, out, Lm1);
}

// Round 3
// 24.097 us; speedup vs baseline: 1.3711x; 1.2254x over previous
//
#include <hip/hip_runtime.h>
#include <stdint.h>

#define N2  361   // 19*19
#define TPB 256

// Flat kernel: thread t owns elements [4t, 4t+4) of the (B*N2) flattened
// problem. Both player-delta tables live in LDS (they depend only on the
// 2-valued player, not on the row), so blocks are row-agnostic.
__global__ __launch_bounds__(TPB)
void superko_flat(const void* __restrict__ legal_p,     // (B,N2) bool/int32/f32
                  const int*  __restrict__ cur_player,  // (B,)
                  const int*  __restrict__ cur_hash,    // (B,)
                  const int*  __restrict__ Z,           // (3,N2)
                  const void* __restrict__ cap_p,       // (B,N2) bool/int32/f32
                  const int*  __restrict__ indptr,      // (B*N2+1,)
                  const int*  __restrict__ cap_idx,     // (L,)
                  int*        __restrict__ out,         // (B,N2)
                  int total, int Lm1, int Bm1)
{
    __shared__ int T01[N2];   // Z0 ^ Z1
    __shared__ int T02[N2];   // Z0 ^ Z2

    for (int t = threadIdx.x; t < N2; t += TPB) {
        int z0 = Z[t], z1 = Z[N2 + t], z2 = Z[2 * N2 + t];
        T01[t] = z0 ^ z1;
        T02[t] = z0 ^ z2;
    }

    // Mask element-width detection: wave-uniform reads of the first 16 words
    // of legal_mask. int32 -> {0,1}; float32 -> {0,0x3f800000}; packed-byte
    // bool masks essentially never match all 16 (P ~ 8^-16).
    const uint32_t* w = (const uint32_t*)legal_p;
    bool layout4 = true;
    #pragma unroll
    for (int k = 0; k < 16; ++k) {
        uint32_t v = w[k];
        layout4 = layout4 && (v == 0u || v == 1u || v == 0x3f800000u);
    }

    __syncthreads();   // tables ready

    const int r0 = (blockIdx.x * TPB + (int)threadIdx.x) * 4;
    if (r0 >= total) return;

    // ---- front-end loads, all independent, issued together ----

    // indptr[r0 .. r0+4]
    const int4 ip = *(const int4*)(indptr + r0);
    const int  ip4 = indptr[r0 + 4];
    const int  se[5] = {ip.x, ip.y, ip.z, ip.w, ip4};

    // masks (vectorized)
    bool keepm[4];
    if (layout4) {
        uint4 l4 = *(const uint4*)((const uint32_t*)legal_p + r0);
        uint4 c4 = *(const uint4*)((const uint32_t*)cap_p   + r0);
        keepm[0] = (l4.x != 0u) & (c4.x != 0u);
        keepm[1] = (l4.y != 0u) & (c4.y != 0u);
        keepm[2] = (l4.z != 0u) & (c4.z != 0u);
        keepm[3] = (l4.w != 0u) & (c4.w != 0u);
    } else {
        uchar4 lb = *(const uchar4*)((const uint8_t*)legal_p + r0);
        uchar4 cb = *(const uchar4*)((const uint8_t*)cap_p   + r0);
        keepm[0] = (lb.x != 0) & (cb.x != 0);
        keepm[1] = (lb.y != 0) & (cb.y != 0);
        keepm[2] = (lb.z != 0) & (cb.z != 0);
        keepm[3] = (lb.w != 0) & (cb.w != 0);
    }

    // row/col decomposition: one divide, then increments. A 4-chunk spans at
    // most 2 rows.
    const unsigned b0 = (unsigned)r0 / 361u;
    const int      i0 = r0 - (int)b0 * 361;
    unsigned b1 = b0 + 1; if (b1 > (unsigned)Bm1) b1 = (unsigned)Bm1;
    const int p0 = cur_player[b0];
    const int h0 = cur_hash[b0];
    const int p1 = cur_player[b1];
    const int h1 = cur_hash[b1];

    int res[4];
    #pragma unroll
    for (int k = 0; k < 4; ++k) {
        const int  iok  = i0 + k;
        const bool wrap = iok >= N2;
        const int  ik   = wrap ? iok - N2 : iok;
        const int  pk   = wrap ? p1 : p0;
        const int  hk   = wrap ? h1 : h0;

        // place delta = Z0^Z[p+1]; capture delta = Z0^Z[2-p]
        const int* placeT = pk ? T02 : T01;
        const int* capT   = pk ? T01 : T02;
        const int  place  = placeT[ik];

        const int s = se[k], e = se[k + 1], len = e - s;
        int acc = 0;
        if (keepm[k] && len > 0) {
            if (len <= 7) {
                // segment length is < 8 by construction; 7 independent
                // clamped loads -> single memory latency.
                int idxs[7];
                #pragma unroll
                for (int t = 0; t < 7; ++t) {
                    int j = s + t;
                    idxs[t] = cap_idx[j > Lm1 ? Lm1 : j];
                }
                #pragma unroll
                for (int t = 0; t < 7; ++t)
                    acc ^= (t < len) ? capT[idxs[t]] : 0;
            } else {
                for (int j = s; j < e; ++j) acc ^= capT[cap_idx[j]];
            }
        }
        res[k] = hk ^ place ^ acc;
    }

    *(int4*)(out + r0) = make_int4(res[0], res[1], res[2], res[3]);
}

extern "C" void kernel_launch(void* const* d_in, const int* in_sizes, int n_in,
                              void* d_out, int out_size, void* d_ws, size_t ws_size,
                              hipStream_t stream) {
    // 0: legal_mask (B,N2)  1: current_player (B,)  2: current_hash (B,)
    // 3: ZposT (3,N2)       4: can_capture_any (B,N2)
    // 5: cap_indptr (B*N2+1,)  6: cap_indices (L,)
    const void* legal  = d_in[0];
    const int*  player = (const int*)d_in[1];
    const int*  hash   = (const int*)d_in[2];
    const int*  Z      = (const int*)d_in[3];
    const void* cap    = d_in[4];
    const int*  indptr = (const int*)d_in[5];
    const int*  capidx = (const int*)d_in[6];
    int*        out    = (int*)d_out;

    const int total = out_size;               // B*N2 = 2,957,312
    const int Lm1   = in_sizes[6] - 1;
    const int Bm1   = in_sizes[1] - 1;

    const int nchunk = (total + 3) / 4;
    const int blocks = (nchunk + TPB - 1) / TPB;   // 2888 for the bench shape

    superko_flat<<<blocks, TPB, 0, stream>>>(legal, player, hash, Z, cap,
                                             indptr, capidx, out,
                                             total, Lm1, Bm1);
}